// Round 9
// baseline (1619.176 us; speedup 1.0000x reference)
//
#include <hip/hip_runtime.h>
#include <math.h>

#define NB 8
#define NN 4096
#define MM 2048
#define KNN_K 16
#define CIN 64
#define COUT 128
#define BN_EPS 1e-5f
#define SENT 0xFFFFFFFFFFFFFFFFull

typedef float v2f __attribute__((ext_vector_type(2)));

__device__ __forceinline__ v2f pk_add(v2f a, v2f b) {
  v2f r;
  asm("v_pk_add_f32 %0, %1, %2" : "=v"(r) : "v"(a), "v"(b));
  return r;
}
__device__ __forceinline__ v2f pk_mul(v2f a, v2f b) {
  v2f r;
  asm("v_pk_mul_f32 %0, %1, %2" : "=v"(r) : "v"(a), "v"(b));
  return r;
}

__device__ __forceinline__ double pack_key(float d, unsigned code) {
  return __longlong_as_double(
      (long long)(((unsigned long long)__float_as_uint(d) << 32) | code));
}
__device__ __forceinline__ unsigned unpack_code(double v) {
  return (unsigned)((unsigned long long)__double_as_longlong(v) &
                    0xFFFFFFFFull);
}

// numpy-exact squared distance: ((dx*dx + dy*dy) + dz*dz), no FMA contraction
__device__ __forceinline__ float sqdist_np(float dx, float dy, float dz) {
  return __fadd_rn(__fadd_rn(__fmul_rn(dx, dx), __fmul_rn(dy, dy)),
                   __fmul_rn(dz, dz));
}

// One DPP reduce level on a positive f64 key (both halves moved with the same
// ctrl). update_dpp keeps `old` in masked-off/invalid lanes -> no-op there.
#define DPP_MAX_LEVEL(best, ctrl, rmask)                                     \
  {                                                                          \
    const int _lo = __builtin_amdgcn_update_dpp(                             \
        __double2loint(best), __double2loint(best), (ctrl), (rmask), 0xf,    \
        false);                                                              \
    const int _hi = __builtin_amdgcn_update_dpp(                             \
        __double2hiint(best), __double2hiint(best), (ctrl), (rmask), 0xf,    \
        false);                                                              \
    best = fmax(best, __hiloint2double(_hi, _lo));                           \
  }
#define DPP_MIN_LEVEL(best, ctrl, rmask)                                     \
  {                                                                          \
    const int _lo = __builtin_amdgcn_update_dpp(                             \
        __double2loint(best), __double2loint(best), (ctrl), (rmask), 0xf,    \
        false);                                                              \
    const int _hi = __builtin_amdgcn_update_dpp(                             \
        __double2hiint(best), __double2hiint(best), (ctrl), (rmask), 0xf,    \
        false);                                                              \
    best = fmin(best, __hiloint2double(_hi, _lo));                           \
  }

// ---------------------------------------------------------------------------
// Fused kernel: blocks 0..7 = FPS (R5-proven inner loop: f64 keys with index
// embedded in low dword, DPP wave reduce); the ONLY change vs the measured
// 1090 us version is the per-step __syncthreads -> sentinel LDS spin sync
// (triple-parity slots; reset schedule proven race-free).
// Blocks 8..519 = GEMM tile (64x128) + BN partial sums -> global atomics.
// ---------------------------------------------------------------------------
__global__ __launch_bounds__(256) void k_fps_gemm(
    const float* __restrict__ pos, const float* __restrict__ x,
    const float* __restrict__ W, const float* __restrict__ bias,
    float* __restrict__ h, float* __restrict__ gsum,
    float* __restrict__ gsumsq, int* __restrict__ fps_idx,
    float* __restrict__ out_pos, float* __restrict__ out_batch) {
  __shared__ __align__(16) char smem_raw[57472];
  const int tid = threadIdx.x;

  if (blockIdx.x < NB) {
    // ------------------------- FPS -------------------------
    float* xs = (float*)smem_raw;          // [4096]
    float* ys = xs + NN;                   // [4096]
    float* zs = ys + NN;                   // [4096]
    int* idxs = (int*)(smem_raw + 49152);  // [2048]
    unsigned long long* slot =
        (unsigned long long*)(smem_raw + 57344);  // [3][4] parity slots
    volatile unsigned long long* vslot = (volatile unsigned long long*)slot;
    const int b = blockIdx.x;
    const float* posc = pos + (size_t)b * NN * 3;
    for (int i = tid; i < NN; i += 256) {
      xs[i] = posc[i * 3 + 0];
      ys[i] = posc[i * 3 + 1];
      zs[i] = posc[i * 3 + 2];
    }
    if (tid < 12) slot[tid] = SENT;
    __syncthreads();

    // thread owns points p = tid*16 + s (contiguous); code = 4095 - p so
    // packed-max tie-breaks to the SMALLEST index (matches jnp.argmax).
    // key[s] = (dmin_bits << 32) | code; lo dword written once, fminf lands
    // in the hi sub-register each step.
    v2f pxv[8], pyv[8], pzv[8];
    double key[16];
    const unsigned code_base = (unsigned)(NN - 1 - tid * 16);
#pragma unroll
    for (int u = 0; u < 8; ++u) {
      const int p = tid * 16 + 2 * u;
      pxv[u] = (v2f){xs[p], xs[p + 1]};
      pyv[u] = (v2f){ys[p], ys[p + 1]};
      pzv[u] = (v2f){zs[p], zs[p + 1]};
    }
#pragma unroll
    for (int s = 0; s < 16; ++s)
      key[s] = __hiloint2double(0x7f800000, (int)(code_base - s));

    const int lane = tid & 63, wv = tid >> 6;
    if (tid == 0) idxs[0] = 0;
    float lx = xs[0], ly = ys[0], lz = zs[0];
    int par = 1;  // m % 3
    for (int m = 1; m < MM; ++m) {
      const v2f nlx = {-lx, -lx}, nly = {-ly, -ly}, nlz = {-lz, -lz};
      double b0 = 0.0, b1 = 0.0, b2 = 0.0, b3 = 0.0;
#pragma unroll
      for (int u = 0; u < 8; ++u) {
        const v2f dx = pk_add(pxv[u], nlx);
        const v2f dy = pk_add(pyv[u], nly);
        const v2f dz = pk_add(pzv[u], nlz);
        const v2f d2 =
            pk_add(pk_add(pk_mul(dx, dx), pk_mul(dy, dy)), pk_mul(dz, dz));
        const int s0 = 2 * u, s1 = 2 * u + 1;
        const float n0 =
            fminf(__int_as_float(__double2hiint(key[s0])), d2.x);
        const float n1 =
            fminf(__int_as_float(__double2hiint(key[s1])), d2.y);
        key[s0] = __hiloint2double(__float_as_int(n0), (int)(code_base - s0));
        key[s1] = __hiloint2double(__float_as_int(n1), (int)(code_base - s1));
        switch (u & 3) {
          case 0: b0 = fmax(b0, fmax(key[s0], key[s1])); break;
          case 1: b1 = fmax(b1, fmax(key[s0], key[s1])); break;
          case 2: b2 = fmax(b2, fmax(key[s0], key[s1])); break;
          default: b3 = fmax(b3, fmax(key[s0], key[s1])); break;
        }
      }
      double best = fmax(fmax(b0, b1), fmax(b2, b3));
      // DPP wave reduce: row rotations then cross-row broadcasts.
      DPP_MAX_LEVEL(best, 0x121, 0xf);  // row_ror:1
      DPP_MAX_LEVEL(best, 0x122, 0xf);  // row_ror:2
      DPP_MAX_LEVEL(best, 0x124, 0xf);  // row_ror:4
      DPP_MAX_LEVEL(best, 0x128, 0xf);  // row_ror:8
      DPP_MAX_LEVEL(best, 0x142, 0xa);  // row_bcast:15 -> rows 1,3
      DPP_MAX_LEVEL(best, 0x143, 0xc);  // row_bcast:31 -> rows 2,3
      // ---- spin sync (replaces __syncthreads; keys never equal SENT) ----
      const int pb = par * 4;
      if (lane == 63)
        vslot[pb + wv] = (unsigned long long)__double_as_longlong(best);
      unsigned long long k0, k1, k2, k3;
      do {
        k0 = vslot[pb + 0];
        k1 = vslot[pb + 1];
        k2 = vslot[pb + 2];
        k3 = vslot[pb + 3];
      } while (k0 == SENT || k1 == SENT || k2 == SENT || k3 == SENT);
      // reset the slot this wave will reuse at step m+2: safe because passing
      // the spin above proves every wave consumed step m-1 (same parity).
      par = (par == 2) ? 0 : par + 1;  // parity of m+1
      if (lane == 63) vslot[(((pb >> 2) + 2) % 3) * 4 + wv] = SENT;
      __threadfence_block();
      const double f =
          fmax(fmax(__longlong_as_double((long long)k0),
                    __longlong_as_double((long long)k1)),
               fmax(__longlong_as_double((long long)k2),
                    __longlong_as_double((long long)k3)));
      const int last = (NN - 1) - (int)unpack_code(f);
      if (tid == 0) idxs[m] = last;
      lx = xs[last];
      ly = ys[last];
      lz = zs[last];
    }
    __syncthreads();
    for (int m = tid; m < MM; m += 256) {
      const int p = idxs[m];
      const int o = b * MM + m;
      fps_idx[o] = p;
      out_pos[o * 3 + 0] = xs[p];
      out_pos[o * 3 + 1] = ys[p];
      out_pos[o * 3 + 2] = zs[p];
      out_batch[o] = (float)b;
    }
  } else {
    // ------------------- GEMM + BN partials -------------------
    float* Wl = (float*)smem_raw;    // [64][128] 32 KB
    float* xl = Wl + CIN * COUT;     // [64][64]  16 KB
    float* bsum = (float*)(smem_raw + 49152);
    float* bsq = bsum + COUT;
    const int bid = blockIdx.x - NB;  // 0..511
    const int r0 = bid * 64;
    for (int i = tid; i < CIN * COUT; i += 256) Wl[i] = W[i];
    for (int i = tid; i < 64 * CIN; i += 256) xl[i] = x[(size_t)r0 * CIN + i];
    if (tid < 2 * COUT) bsum[tid] = 0.f;
    __syncthreads();
    const int cg = tid & 31, rg = tid >> 5;
    const int c = cg * 4;
    float acc[8][4];
#pragma unroll
    for (int j = 0; j < 8; ++j)
#pragma unroll
      for (int t = 0; t < 4; ++t) acc[j][t] = 0.f;
    for (int k = 0; k < CIN; ++k) {
      const float4 wk = *(const float4*)&Wl[k * COUT + c];
#pragma unroll
      for (int j = 0; j < 8; ++j) {
        const float xv = xl[(rg * 8 + j) * CIN + k];
        acc[j][0] = fmaf(xv, wk.x, acc[j][0]);
        acc[j][1] = fmaf(xv, wk.y, acc[j][1]);
        acc[j][2] = fmaf(xv, wk.z, acc[j][2]);
        acc[j][3] = fmaf(xv, wk.w, acc[j][3]);
      }
    }
    const float4 bb = *(const float4*)&bias[c];
    float s0 = 0, s1 = 0, s2 = 0, s3 = 0, q0 = 0, q1 = 0, q2 = 0, q3 = 0;
#pragma unroll
    for (int j = 0; j < 8; ++j) {
      float4 hv;
      hv.x = acc[j][0] + bb.x;
      hv.y = acc[j][1] + bb.y;
      hv.z = acc[j][2] + bb.z;
      hv.w = acc[j][3] + bb.w;
      *(float4*)&h[(size_t)(r0 + rg * 8 + j) * COUT + c] = hv;
      s0 += hv.x; s1 += hv.y; s2 += hv.z; s3 += hv.w;
      q0 += hv.x * hv.x; q1 += hv.y * hv.y;
      q2 += hv.z * hv.z; q3 += hv.w * hv.w;
    }
    atomicAdd(&bsum[c + 0], s0); atomicAdd(&bsum[c + 1], s1);
    atomicAdd(&bsum[c + 2], s2); atomicAdd(&bsum[c + 3], s3);
    atomicAdd(&bsq[c + 0], q0);  atomicAdd(&bsq[c + 1], q1);
    atomicAdd(&bsq[c + 2], q2);  atomicAdd(&bsq[c + 3], q3);
    __syncthreads();
    if (tid < COUT) {
      atomicAdd(&gsum[tid], bsum[tid]);
      atomicAdd(&gsumsq[tid], bsq[tid]);
    }
  }
}

// ---------------------------------------------------------------------------
__device__ __forceinline__ float gelu_exact(float v) {
  return 0.5f * v * (1.0f + erff(v * 0.70710678118654752f));
}

// BN finalize fused in: every block derives scale/shift from the global sums.
__global__ __launch_bounds__(256) void k_act(float* __restrict__ h,
                                             const float* __restrict__ gsum,
                                             const float* __restrict__ gsumsq,
                                             const float* __restrict__ gamma,
                                             const float* __restrict__ beta) {
  __shared__ float sc[COUT], sh[COUT];
  const int t = threadIdx.x;
  if (t < COUT) {
    const float n = (float)(NB * NN);
    const float mu = gsum[t] / n;
    const float var = gsumsq[t] / n - mu * mu;
    const float rs = rsqrtf(var + BN_EPS);
    const float s = rs * gamma[t];
    sc[t] = s;
    sh[t] = beta[t] - mu * s;
  }
  __syncthreads();
  const int g = blockIdx.x * 256 + t;  // float4 index
  const int c = (g & 31) * 4;
  float4* h4 = (float4*)h;
  float4 v = h4[g];
  const float4 s4 = *(const float4*)&sc[c];
  const float4 b4 = *(const float4*)&sh[c];
  v.x = gelu_exact(v.x * s4.x + b4.x);
  v.y = gelu_exact(v.y * s4.y + b4.y);
  v.z = gelu_exact(v.z * s4.z + b4.z);
  v.w = gelu_exact(v.w * s4.w + b4.w);
  h4[g] = v;
}

// ---------------------------------------------------------------------------
// One wave per query: exact KNN via 16x min-extraction (f64 DPP reduce +
// readlane) over LDS-cached distances, then max-pool of the 16 neighbors'
// 128-ch feature rows (h already BN+GELU'd by k_act).
// ---------------------------------------------------------------------------
__global__ __launch_bounds__(256) void k_knn(const float* __restrict__ pos,
                                             const int* __restrict__ fps_idx,
                                             const float* __restrict__ h,
                                             float* __restrict__ out_x) {
  __shared__ float dc[4][NN];  // 64 KB
  const int tid = threadIdx.x, lane = tid & 63, wv = tid >> 6;
  const int q = blockIdx.x * 4 + wv;
  const int b = q >> 11, m = q & (MM - 1);
  const int qi = fps_idx[b * MM + m];
  const float* posc = pos + (size_t)b * NN * 3;
  const float qx = posc[qi * 3 + 0], qy = posc[qi * 3 + 1],
              qz = posc[qi * 3 + 2];
  float* dcw = dc[wv];
  const double DINF = __longlong_as_double(0x7FF0000000000000LL);
  double gmin[8];
#pragma unroll
  for (int g = 0; g < 8; ++g) gmin[g] = DINF;
#pragma unroll
  for (int s = 0; s < 64; ++s) {
    const int p = s * 64 + lane;  // owner of p is lane (p % 64)
    const float d = sqdist_np(posc[p * 3 + 0] - qx, posc[p * 3 + 1] - qy,
                              posc[p * 3 + 2] - qz);
    dcw[p] = d;
    gmin[s >> 3] = fmin(gmin[s >> 3], pack_key(d, (unsigned)p));
  }
  double lmin = gmin[0];
#pragma unroll
  for (int g = 1; g < 8; ++g) lmin = fmin(lmin, gmin[g]);

  int nbr[KNN_K];
#pragma unroll
  for (int r = 0; r < KNN_K; ++r) {
    double v = lmin;
    DPP_MIN_LEVEL(v, 0x121, 0xf);  // row_ror:1
    DPP_MIN_LEVEL(v, 0x122, 0xf);  // row_ror:2
    DPP_MIN_LEVEL(v, 0x124, 0xf);  // row_ror:4
    DPP_MIN_LEVEL(v, 0x128, 0xf);  // row_ror:8
    DPP_MIN_LEVEL(v, 0x142, 0xa);  // row_bcast:15 -> rows 1,3
    DPP_MIN_LEVEL(v, 0x143, 0xc);  // row_bcast:31 -> rows 2,3
    // lane 63 holds the wave min; its low dword is the winning point index
    const unsigned p =
        (unsigned)__builtin_amdgcn_readlane(__double2loint(v), 63);
    nbr[r] = (int)p;
    if (lane == (int)(p & 63)) {
      dcw[p] = __int_as_float(0x7f800000);  // remove from candidates
      const int g = (int)(p >> 9);
      double nm = DINF;
      const int base = g * 8 * 64 + lane;
#pragma unroll
      for (int j = 0; j < 8; ++j) {
        const int pp = base + j * 64;
        nm = fmin(nm, pack_key(dcw[pp], (unsigned)pp));
      }
#pragma unroll
      for (int gg = 0; gg < 8; ++gg)
        if (gg == g) gmin[gg] = nm;
      lmin = gmin[0];
#pragma unroll
      for (int gg = 1; gg < 8; ++gg) lmin = fmin(lmin, gmin[gg]);
    }
  }

  const float* hb = h + (size_t)b * NN * COUT;
  float f0 = -__int_as_float(0x7f800000), f1 = f0;
#pragma unroll
  for (int r = 0; r < KNN_K; ++r) {
    const float* row = hb + (size_t)nbr[r] * COUT;
    f0 = fmaxf(f0, row[lane]);
    f1 = fmaxf(f1, row[lane + 64]);
  }
  out_x[(size_t)q * COUT + lane] = f0;
  out_x[(size_t)q * COUT + lane + 64] = f1;
}

// ---------------------------------------------------------------------------
extern "C" void kernel_launch(void* const* d_in, const int* in_sizes, int n_in,
                              void* d_out, int out_size, void* d_ws,
                              size_t ws_size, hipStream_t stream) {
  const float* x = (const float*)d_in[0];
  const float* pos = (const float*)d_in[1];
  // d_in[2] = batch (unused; implied by layout)
  const float* W = (const float*)d_in[3];
  const float* bias = (const float*)d_in[4];
  const float* gamma = (const float*)d_in[5];
  const float* beta = (const float*)d_in[6];

  float* out_x = (float*)d_out;                          // [B*M,128]
  float* out_pos = out_x + (size_t)NB * MM * COUT;       // [B*M,3]
  float* out_batch = out_pos + (size_t)NB * MM * 3;      // [B*M]

  char* ws = (char*)d_ws;
  float* h = (float*)ws;                                 // 16 MB
  float* gsum = (float*)(ws + (size_t)16777216);
  float* gsumsq = gsum + COUT;
  int* fps_idx = (int*)(gsumsq + COUT);                  // B*M ints

  (void)hipMemsetAsync(gsum, 0, 2 * COUT * sizeof(float), stream);
  hipLaunchKernelGGL(k_fps_gemm, dim3(NB + 512), dim3(256), 0, stream, pos, x,
                     W, bias, h, gsum, gsumsq, fps_idx, out_pos, out_batch);
  hipLaunchKernelGGL(k_act, dim3(4096), dim3(256), 0, stream, h, gsum, gsumsq,
                     gamma, beta);
  hipLaunchKernelGGL(k_knn, dim3(4096), dim3(256), 0, stream, pos, fps_idx, h,
                     out_x);
}

// Round 10
// 1237.199 us; speedup vs baseline: 1.3087x; 1.3087x over previous
//
#include <hip/hip_runtime.h>
#include <math.h>

#define NB 8
#define NN 4096
#define MM 2048
#define KNN_K 16
#define CIN 64
#define COUT 128
#define BN_EPS 1e-5f

typedef float v2f __attribute__((ext_vector_type(2)));

__device__ __forceinline__ v2f pk_add(v2f a, v2f b) {
  v2f r;
  asm("v_pk_add_f32 %0, %1, %2" : "=v"(r) : "v"(a), "v"(b));
  return r;
}
__device__ __forceinline__ v2f pk_mul(v2f a, v2f b) {
  v2f r;
  asm("v_pk_mul_f32 %0, %1, %2" : "=v"(r) : "v"(a), "v"(b));
  return r;
}

__device__ __forceinline__ double pack_key(float d, unsigned code) {
  return __longlong_as_double(
      (long long)(((unsigned long long)__float_as_uint(d) << 32) | code));
}
__device__ __forceinline__ unsigned unpack_code(double v) {
  return (unsigned)((unsigned long long)__double_as_longlong(v) &
                    0xFFFFFFFFull);
}

// numpy-exact squared distance: ((dx*dx + dy*dy) + dz*dz), no FMA contraction
__device__ __forceinline__ float sqdist_np(float dx, float dy, float dz) {
  return __fadd_rn(__fadd_rn(__fmul_rn(dx, dx), __fmul_rn(dy, dy)),
                   __fmul_rn(dz, dz));
}

// One DPP reduce level on a positive f64 key (both halves moved with the same
// ctrl). update_dpp keeps `old` in masked-off/invalid lanes -> no-op there.
#define DPP_MAX_LEVEL(best, ctrl, rmask)                                     \
  {                                                                          \
    const int _lo = __builtin_amdgcn_update_dpp(                             \
        __double2loint(best), __double2loint(best), (ctrl), (rmask), 0xf,    \
        false);                                                              \
    const int _hi = __builtin_amdgcn_update_dpp(                             \
        __double2hiint(best), __double2hiint(best), (ctrl), (rmask), 0xf,    \
        false);                                                              \
    best = fmax(best, __hiloint2double(_hi, _lo));                           \
  }
#define DPP_MIN_LEVEL(best, ctrl, rmask)                                     \
  {                                                                          \
    const int _lo = __builtin_amdgcn_update_dpp(                             \
        __double2loint(best), __double2loint(best), (ctrl), (rmask), 0xf,    \
        false);                                                              \
    const int _hi = __builtin_amdgcn_update_dpp(                             \
        __double2hiint(best), __double2hiint(best), (ctrl), (rmask), 0xf,    \
        false);                                                              \
    best = fmin(best, __hiloint2double(_hi, _lo));                           \
  }

// ---------------------------------------------------------------------------
// Fused kernel: blocks 0..7 = FPS — BYTE-EXACT copy of the R5 structure that
// measured 1090 us (f64 keys w/ embedded index, fminf into hi-dword, DPP wave
// reduce, 4 parity LDS slots, one s_barrier per step). Five measured variants
// (LDS atomics / 512thr / cndmask chain / select tree / spin sync) all lost.
// Blocks 8..519 = GEMM tile (64x128) + BN partial sums -> global atomics.
// ---------------------------------------------------------------------------
__global__ __launch_bounds__(256) void k_fps_gemm(
    const float* __restrict__ pos, const float* __restrict__ x,
    const float* __restrict__ W, const float* __restrict__ bias,
    float* __restrict__ h, float* __restrict__ gsum,
    float* __restrict__ gsumsq, int* __restrict__ fps_idx,
    float* __restrict__ out_pos, float* __restrict__ out_batch) {
  __shared__ __align__(16) char smem_raw[57472];
  const int tid = threadIdx.x;

  if (blockIdx.x < NB) {
    // ------------------------- FPS -------------------------
    float* xs = (float*)smem_raw;          // [4096]
    float* ys = xs + NN;                   // [4096]
    float* zs = ys + NN;                   // [4096]
    int* idxs = (int*)(smem_raw + 49152);  // [2048]
    double* red = (double*)(smem_raw + 57344);  // [2][4] parity buffered
    const int b = blockIdx.x;
    const float* posc = pos + (size_t)b * NN * 3;
    for (int i = tid; i < NN; i += 256) {
      xs[i] = posc[i * 3 + 0];
      ys[i] = posc[i * 3 + 1];
      zs[i] = posc[i * 3 + 2];
    }
    __syncthreads();

    // thread owns points p = tid*16 + s (contiguous); code = 4095 - p so
    // packed-max tie-breaks to the SMALLEST index (matches jnp.argmax).
    // key[s] = (dmin_bits << 32) | code; lo dword written once, fminf lands
    // in the hi sub-register each step.
    v2f pxv[8], pyv[8], pzv[8];
    double key[16];
    const unsigned code_base = (unsigned)(NN - 1 - tid * 16);
#pragma unroll
    for (int u = 0; u < 8; ++u) {
      const int p = tid * 16 + 2 * u;
      pxv[u] = (v2f){xs[p], xs[p + 1]};
      pyv[u] = (v2f){ys[p], ys[p + 1]};
      pzv[u] = (v2f){zs[p], zs[p + 1]};
    }
#pragma unroll
    for (int s = 0; s < 16; ++s)
      key[s] = __hiloint2double(0x7f800000, (int)(code_base - s));

    const int lane = tid & 63, wv = tid >> 6;
    int last = 0;
    if (tid == 0) idxs[0] = 0;
    float lx = xs[0], ly = ys[0], lz = zs[0];
    for (int m = 1; m < MM; ++m) {
      const v2f nlx = {-lx, -lx}, nly = {-ly, -ly}, nlz = {-lz, -lz};
      double b0 = 0.0, b1 = 0.0, b2 = 0.0, b3 = 0.0;
#pragma unroll
      for (int u = 0; u < 8; ++u) {
        const v2f dx = pk_add(pxv[u], nlx);
        const v2f dy = pk_add(pyv[u], nly);
        const v2f dz = pk_add(pzv[u], nlz);
        const v2f d2 =
            pk_add(pk_add(pk_mul(dx, dx), pk_mul(dy, dy)), pk_mul(dz, dz));
        const int s0 = 2 * u, s1 = 2 * u + 1;
        const float n0 =
            fminf(__int_as_float(__double2hiint(key[s0])), d2.x);
        const float n1 =
            fminf(__int_as_float(__double2hiint(key[s1])), d2.y);
        key[s0] = __hiloint2double(__float_as_int(n0), (int)(code_base - s0));
        key[s1] = __hiloint2double(__float_as_int(n1), (int)(code_base - s1));
        switch (u & 3) {
          case 0: b0 = fmax(b0, fmax(key[s0], key[s1])); break;
          case 1: b1 = fmax(b1, fmax(key[s0], key[s1])); break;
          case 2: b2 = fmax(b2, fmax(key[s0], key[s1])); break;
          default: b3 = fmax(b3, fmax(key[s0], key[s1])); break;
        }
      }
      double best = fmax(fmax(b0, b1), fmax(b2, b3));
      // DPP wave reduce: row rotations then cross-row broadcasts.
      DPP_MAX_LEVEL(best, 0x121, 0xf);  // row_ror:1
      DPP_MAX_LEVEL(best, 0x122, 0xf);  // row_ror:2
      DPP_MAX_LEVEL(best, 0x124, 0xf);  // row_ror:4
      DPP_MAX_LEVEL(best, 0x128, 0xf);  // row_ror:8
      DPP_MAX_LEVEL(best, 0x142, 0xa);  // row_bcast:15 -> rows 1,3
      DPP_MAX_LEVEL(best, 0x143, 0xc);  // row_bcast:31 -> rows 2,3
      const int par = (m & 1) * 4;
      if (lane == 63) red[par + wv] = best;  // lane 63 holds wave max
      __syncthreads();
      const double f = fmax(fmax(red[par + 0], red[par + 1]),
                            fmax(red[par + 2], red[par + 3]));
      last = (NN - 1) - (int)unpack_code(f);
      if (tid == 0) idxs[m] = last;
      lx = xs[last];
      ly = ys[last];
      lz = zs[last];
    }
    __syncthreads();
    for (int m = tid; m < MM; m += 256) {
      const int p = idxs[m];
      const int o = b * MM + m;
      fps_idx[o] = p;
      out_pos[o * 3 + 0] = xs[p];
      out_pos[o * 3 + 1] = ys[p];
      out_pos[o * 3 + 2] = zs[p];
      out_batch[o] = (float)b;
    }
  } else {
    // ------------------- GEMM + BN partials -------------------
    float* Wl = (float*)smem_raw;    // [64][128] 32 KB
    float* xl = Wl + CIN * COUT;     // [64][64]  16 KB
    float* bsum = (float*)(smem_raw + 49152);
    float* bsq = bsum + COUT;
    const int bid = blockIdx.x - NB;  // 0..511
    const int r0 = bid * 64;
    for (int i = tid; i < CIN * COUT; i += 256) Wl[i] = W[i];
    for (int i = tid; i < 64 * CIN; i += 256) xl[i] = x[(size_t)r0 * CIN + i];
    if (tid < 2 * COUT) bsum[tid] = 0.f;
    __syncthreads();
    const int cg = tid & 31, rg = tid >> 5;
    const int c = cg * 4;
    float acc[8][4];
#pragma unroll
    for (int j = 0; j < 8; ++j)
#pragma unroll
      for (int t = 0; t < 4; ++t) acc[j][t] = 0.f;
    for (int k = 0; k < CIN; ++k) {
      const float4 wk = *(const float4*)&Wl[k * COUT + c];
#pragma unroll
      for (int j = 0; j < 8; ++j) {
        const float xv = xl[(rg * 8 + j) * CIN + k];
        acc[j][0] = fmaf(xv, wk.x, acc[j][0]);
        acc[j][1] = fmaf(xv, wk.y, acc[j][1]);
        acc[j][2] = fmaf(xv, wk.z, acc[j][2]);
        acc[j][3] = fmaf(xv, wk.w, acc[j][3]);
      }
    }
    const float4 bb = *(const float4*)&bias[c];
    float s0 = 0, s1 = 0, s2 = 0, s3 = 0, q0 = 0, q1 = 0, q2 = 0, q3 = 0;
#pragma unroll
    for (int j = 0; j < 8; ++j) {
      float4 hv;
      hv.x = acc[j][0] + bb.x;
      hv.y = acc[j][1] + bb.y;
      hv.z = acc[j][2] + bb.z;
      hv.w = acc[j][3] + bb.w;
      *(float4*)&h[(size_t)(r0 + rg * 8 + j) * COUT + c] = hv;
      s0 += hv.x; s1 += hv.y; s2 += hv.z; s3 += hv.w;
      q0 += hv.x * hv.x; q1 += hv.y * hv.y;
      q2 += hv.z * hv.z; q3 += hv.w * hv.w;
    }
    atomicAdd(&bsum[c + 0], s0); atomicAdd(&bsum[c + 1], s1);
    atomicAdd(&bsum[c + 2], s2); atomicAdd(&bsum[c + 3], s3);
    atomicAdd(&bsq[c + 0], q0);  atomicAdd(&bsq[c + 1], q1);
    atomicAdd(&bsq[c + 2], q2);  atomicAdd(&bsq[c + 3], q3);
    __syncthreads();
    if (tid < COUT) {
      atomicAdd(&gsum[tid], bsum[tid]);
      atomicAdd(&gsumsq[tid], bsq[tid]);
    }
  }
}

// ---------------------------------------------------------------------------
__device__ __forceinline__ float gelu_exact(float v) {
  return 0.5f * v * (1.0f + erff(v * 0.70710678118654752f));
}

// ---------------------------------------------------------------------------
// One wave per query: exact KNN via 16x min-extraction (f64 DPP reduce +
// readlane) over LDS-cached distances. BN+GELU folded into the max-pool via
// the EXACT quasiconvexity identity: gelu is decreasing-then-increasing, so
// max_r gelu(y_r) = max(gelu(min y), gelu(max y)) — track min AND max of the
// raw h values, 2 gelu evals per channel. No separate k_act pass over h.
// XCD swizzle: cloud = blockIdx & 7, so each XCD's L2 caches one cloud's
// 2 MB h-slice (fits 4 MB L2) + 48 KB pos.
// ---------------------------------------------------------------------------
__global__ __launch_bounds__(256) void k_knn(
    const float* __restrict__ pos, const int* __restrict__ fps_idx,
    const float* __restrict__ h, const float* __restrict__ gsum,
    const float* __restrict__ gsumsq, const float* __restrict__ gamma,
    const float* __restrict__ beta, float* __restrict__ out_x) {
  __shared__ float dc[4][NN];  // 64 KB
  __shared__ float sc[COUT], sh[COUT];
  const int tid = threadIdx.x, lane = tid & 63, wv = tid >> 6;
  if (tid < COUT) {
    const float n = (float)(NB * NN);
    const float mu = gsum[tid] / n;
    const float var = gsumsq[tid] / n - mu * mu;
    const float rs = rsqrtf(var + BN_EPS);
    const float s = rs * gamma[tid];
    sc[tid] = s;
    sh[tid] = beta[tid] - mu * s;
  }
  __syncthreads();
  const int b = blockIdx.x & 7;                        // XCD-aligned cloud
  const int m = (blockIdx.x >> 3) * 4 + wv;            // query within cloud
  const int q = b * MM + m;
  const int qi = fps_idx[q];
  const float* posc = pos + (size_t)b * NN * 3;
  const float qx = posc[qi * 3 + 0], qy = posc[qi * 3 + 1],
              qz = posc[qi * 3 + 2];
  float* dcw = dc[wv];
  const double DINF = __longlong_as_double(0x7FF0000000000000LL);
  double gmin[8];
#pragma unroll
  for (int g = 0; g < 8; ++g) gmin[g] = DINF;
#pragma unroll
  for (int s = 0; s < 64; ++s) {
    const int p = s * 64 + lane;  // owner of p is lane (p % 64)
    const float d = sqdist_np(posc[p * 3 + 0] - qx, posc[p * 3 + 1] - qy,
                              posc[p * 3 + 2] - qz);
    dcw[p] = d;
    gmin[s >> 3] = fmin(gmin[s >> 3], pack_key(d, (unsigned)p));
  }
  double lmin = gmin[0];
#pragma unroll
  for (int g = 1; g < 8; ++g) lmin = fmin(lmin, gmin[g]);

  int nbr[KNN_K];
#pragma unroll
  for (int r = 0; r < KNN_K; ++r) {
    double v = lmin;
    DPP_MIN_LEVEL(v, 0x121, 0xf);  // row_ror:1
    DPP_MIN_LEVEL(v, 0x122, 0xf);  // row_ror:2
    DPP_MIN_LEVEL(v, 0x124, 0xf);  // row_ror:4
    DPP_MIN_LEVEL(v, 0x128, 0xf);  // row_ror:8
    DPP_MIN_LEVEL(v, 0x142, 0xa);  // row_bcast:15 -> rows 1,3
    DPP_MIN_LEVEL(v, 0x143, 0xc);  // row_bcast:31 -> rows 2,3
    // lane 63 holds the wave min; its low dword is the winning point index
    const unsigned p =
        (unsigned)__builtin_amdgcn_readlane(__double2loint(v), 63);
    nbr[r] = (int)p;
    if (lane == (int)(p & 63)) {
      dcw[p] = __int_as_float(0x7f800000);  // remove from candidates
      const int g = (int)(p >> 9);
      double nm = DINF;
      const int base = g * 8 * 64 + lane;
#pragma unroll
      for (int j = 0; j < 8; ++j) {
        const int pp = base + j * 64;
        nm = fmin(nm, pack_key(dcw[pp], (unsigned)pp));
      }
#pragma unroll
      for (int gg = 0; gg < 8; ++gg)
        if (gg == g) gmin[gg] = nm;
      lmin = gmin[0];
#pragma unroll
      for (int gg = 1; gg < 8; ++gg) lmin = fmin(lmin, gmin[gg]);
    }
  }

  // min/max pool of raw h, then 2 gelu evals per channel (exact identity)
  const float* hb = h + (size_t)b * NN * COUT;
  const float PINF = __int_as_float(0x7f800000);
  float mx0 = -PINF, mn0 = PINF, mx1 = -PINF, mn1 = PINF;
#pragma unroll
  for (int r = 0; r < KNN_K; ++r) {
    const float* row = hb + (size_t)nbr[r] * COUT;
    const float a = row[lane], c = row[lane + 64];
    mx0 = fmaxf(mx0, a);
    mn0 = fminf(mn0, a);
    mx1 = fmaxf(mx1, c);
    mn1 = fminf(mn1, c);
  }
  const float sc0 = sc[lane], sh0 = sh[lane];
  const float sc1 = sc[lane + 64], sh1 = sh[lane + 64];
  const float o0 = fmaxf(gelu_exact(fmaf(mx0, sc0, sh0)),
                         gelu_exact(fmaf(mn0, sc0, sh0)));
  const float o1 = fmaxf(gelu_exact(fmaf(mx1, sc1, sh1)),
                         gelu_exact(fmaf(mn1, sc1, sh1)));
  out_x[(size_t)q * COUT + lane] = o0;
  out_x[(size_t)q * COUT + lane + 64] = o1;
}

// ---------------------------------------------------------------------------
extern "C" void kernel_launch(void* const* d_in, const int* in_sizes, int n_in,
                              void* d_out, int out_size, void* d_ws,
                              size_t ws_size, hipStream_t stream) {
  const float* x = (const float*)d_in[0];
  const float* pos = (const float*)d_in[1];
  // d_in[2] = batch (unused; implied by layout)
  const float* W = (const float*)d_in[3];
  const float* bias = (const float*)d_in[4];
  const float* gamma = (const float*)d_in[5];
  const float* beta = (const float*)d_in[6];

  float* out_x = (float*)d_out;                          // [B*M,128]
  float* out_pos = out_x + (size_t)NB * MM * COUT;       // [B*M,3]
  float* out_batch = out_pos + (size_t)NB * MM * 3;      // [B*M]

  char* ws = (char*)d_ws;
  float* h = (float*)ws;                                 // 16 MB (raw GEMM)
  float* gsum = (float*)(ws + (size_t)16777216);
  float* gsumsq = gsum + COUT;
  int* fps_idx = (int*)(gsumsq + COUT);                  // B*M ints

  (void)hipMemsetAsync(gsum, 0, 2 * COUT * sizeof(float), stream);
  hipLaunchKernelGGL(k_fps_gemm, dim3(NB + 512), dim3(256), 0, stream, pos, x,
                     W, bias, h, gsum, gsumsq, fps_idx, out_pos, out_batch);
  hipLaunchKernelGGL(k_knn, dim3(4096), dim3(256), 0, stream, pos, fps_idx, h,
                     gsum, gsumsq, gamma, beta, out_x);
}